// Round 17
// baseline (211.669 us; speedup 1.0000x reference)
//
#include <hip/hip_runtime.h>
#include <hip/hip_bf16.h>

typedef __attribute__((ext_vector_type(8))) short short8;
typedef __attribute__((ext_vector_type(4))) float f32x4;
typedef __attribute__((ext_vector_type(4))) int i32x4;
typedef unsigned short u16;
typedef unsigned int u32;
typedef __attribute__((ext_vector_type(8))) unsigned short u16x8;
typedef __attribute__((ext_vector_type(4))) u32 u32x4;

#define XN 16
#define XC 64
#define XH 256
#define XW 256
#define XO 64
#define CH_STRIDE (XH * XW)   // 65536

// ---- i8 path ws layout (bytes) ----
#define QX_OFF    0                         // i8[16*256*256*64] = 67,108,864 (pixel-major NHWC)
#define INVS_OFF  67108864                  // f32[1048576] = 4,194,304
#define WBUF_OFF  71303168                  // i8[36864]
#define PART_OFF  71340032                  // f32[64]
#define WM_OFF    71340288                  // f32[1]
#define WS_NEED   71340544

// ---------------------------------------------------------------------------
// Weight quant stage 1: deterministic partial |w| sums (64 blocks x 576 elems).
// ---------------------------------------------------------------------------
__global__ __launch_bounds__(256) void wq_reduce(const float* __restrict__ w,
                                                 float* __restrict__ partials) {
    __shared__ float red[4];
    const int tid = threadIdx.x;
    const int base = blockIdx.x * 576;       // 36864 / 64
    float s = 0.f;
    for (int i = tid; i < 576; i += 256) s += fabsf(w[base + i]);
    #pragma unroll
    for (int off = 32; off > 0; off >>= 1) s += __shfl_down(s, off, 64);
    if ((tid & 63) == 0) red[tid >> 6] = s;
    __syncthreads();
    if (tid == 0) partials[blockIdx.x] = red[0] + red[1] + red[2] + red[3];
}

// ---------------------------------------------------------------------------
// Weight quant stage 2: ternarize to i8 in MFMA A-fragment layout (144 blocks).
//   idx = ((t*4 + m)*64 + l)*16 + j
//   holds tern[o = m*16 + (l&15)][i = (l>>4)*16 + j]  for tap t
// ---------------------------------------------------------------------------
__global__ __launch_bounds__(256) void wq_tern_i8(const float* __restrict__ w,
                                                  const float* __restrict__ partials,
                                                  float* __restrict__ wm_out,
                                                  signed char* __restrict__ wbuf) {
    __shared__ float wm_sh;
    const int tid = threadIdx.x;
    if (tid == 0) {
        float tot = 0.f;
        #pragma unroll
        for (int i = 0; i < 64; ++i) tot += partials[i];   // fixed order: deterministic
        float wm = fmaxf(tot / (float)(XO * XC * 9), 1e-5f);
        wm_sh = wm;
        if (blockIdx.x == 0) wm_out[0] = wm;
    }
    __syncthreads();
    const float wscale = 1.0f / wm_sh;

    const int idx = blockIdx.x * 256 + tid;  // < 36864
    const int j = idx & 15;
    const int l = (idx >> 4) & 63;
    const int m = (idx >> 10) & 3;
    const int t = idx >> 12;                 // 0..8
    const int o = m * 16 + (l & 15);
    const int i = (l >> 4) * 16 + j;
    const int kh = t / 3, kw = t % 3;
    const float wv = w[((o * XC + i) * 3 + kh) * 3 + kw];
    const float tern = fminf(fmaxf(rintf(wv * wscale), -1.f), 1.f);
    wbuf[idx] = (signed char)(int)tern;
}

// ---------------------------------------------------------------------------
// Activation quant: one block per (n,h) row. qx = i8, pixel-major (64 B/px,
// channels contiguous). invs = amax/127 per pixel.
// ---------------------------------------------------------------------------
__global__ __launch_bounds__(256) void aq_i8(const float* __restrict__ x,
                                             signed char* __restrict__ qx,
                                             float* __restrict__ invs) {
    const int tid = threadIdx.x;
    const int b = blockIdx.x;            // 4096 = 16*256
    const int n = b >> 8;

    const float* px = x + ((size_t)n << 22) + ((size_t)(b & 255) << 8) + tid;
    float vals[64];
    float amax = 0.f;
    #pragma unroll
    for (int c = 0; c < 64; ++c) {
        const float v = px[(size_t)c << 16];
        vals[c] = v;
        amax = fmaxf(amax, fabsf(v));
    }
    const float am = fmaxf(amax, 1e-5f);
    const float scale = 127.0f / am;
    invs[((size_t)b << 8) + tid] = am * (1.0f / 127.0f);

    u32 words[16];
    #pragma unroll
    for (int wk = 0; wk < 16; ++wk) {
        u32 acc = 0;
        #pragma unroll
        for (int bb = 0; bb < 4; ++bb) {
            const float q = fminf(fmaxf(rintf(vals[wk * 4 + bb] * scale), -128.f), 127.f);
            acc |= ((u32)((int)q) & 255u) << (bb * 8);
        }
        words[wk] = acc;
    }
    u32* dst = (u32*)(qx + ((((size_t)b << 8) + tid) << 6));
    #pragma unroll
    for (int i = 0; i < 4; ++i) {
        *reinterpret_cast<u32x4*>(dst + i * 4) =
            (u32x4){words[i * 4], words[i * 4 + 1], words[i * 4 + 2], words[i * 4 + 3]};
    }
}

// ---------------------------------------------------------------------------
// Conv v14 (= round-16 structure; ONLY change: nontemporal stores -> regular
// cached stores). Rationale: NT bypasses L2/L3 and commits synchronously to
// HBM; regular full-128B-line stores complete at L2 (~34 TB/s), write-combine
// there, and flush to HBM lazily — overlapping later blocks and the next
// kernel. Single-variable A/B against the 164.4 µs round-16 baseline.
// ---------------------------------------------------------------------------
__global__ __launch_bounds__(256, 2) void conv_i8(const signed char* __restrict__ qx,
                                                  const float* __restrict__ invs,
                                                  const signed char* __restrict__ wbuf,
                                                  const float* __restrict__ wm_ptr,
                                                  const float* __restrict__ bias,
                                                  float* __restrict__ out) {
    __shared__ float eplds[4][64][36];   // 36,864 B; per-wave private, reused per row

    const int tid = threadIdx.x;
    // bijective XCD swizzle: 4096 blocks, 512 per XCD
    const int bid = (blockIdx.x & 7) * 512 + (blockIdx.x >> 3);
    const int n      = bid >> 8;           // 256 blocks/image
    const int rem    = bid & 255;
    const int rowgrp = rem >> 3;           // 0..31 (8 rows each)
    const int w0     = (rem & 7) << 5;     // 0..224
    const int wv     = tid >> 6;
    const int gh0    = (rowgrp << 3) + (wv << 1);  // wave's first output row
    const int lane = tid & 63;
    const int l15 = lane & 15;
    const int lg  = lane >> 4;

    const signed char* qn = qx + ((size_t)n << 22);          // n * 256*256*64
    const float*       in = invs + ((size_t)n << 16);

    // per-lane clamped cols for nt in {0,1}, dw in {0,1,2}
    int gwc[2][3]; bool cok[2][3];
    #pragma unroll
    for (int nt = 0; nt < 2; ++nt)
        #pragma unroll
        for (int dw = 0; dw < 3; ++dw) {
            const int gw = w0 + nt * 16 + l15 + dw - 1;
            cok[nt][dw] = (gw >= 0) & (gw < XW);
            gwc[nt][dw] = min(max(gw, 0), XW - 1);
        }
    // IV row-load column: lane covers halo cols w0-1 .. w0+62 (need w0-1..w0+33)
    const int ivcol = min(max(w0 + lane - 1, 0), XW - 1);

    // ---- addresses for the mega-batch ----
    const signed char* ap[4][3][2];
    const float*       ip[4];
    bool rokv[4];
    #pragma unroll
    for (int w = 0; w < 4; ++w) {
        const int gh = gh0 + w - 1;
        rokv[w] = (gh >= 0) & (gh < XH);
        const int ghc = min(max(gh, 0), XH - 1);
        const signed char* qrow = qn + ((size_t)ghc << 14);   // 256 px * 64 B
        ip[w] = in + (ghc << 8) + ivcol;
        #pragma unroll
        for (int dw = 0; dw < 3; ++dw)
            #pragma unroll
            for (int nt = 0; nt < 2; ++nt)
                ap[w][dw][nt] = qrow + (gwc[nt][dw] << 6) + (lg << 4);
    }

    // ---- THE batch: 24 dwordx4 + 4 dword in ONE asm statement, drained inside
    i32x4 B[4][3][2];
    float IVw[4];
    asm volatile(
        "global_load_dwordx4 %0, %28, off\n\t"
        "global_load_dwordx4 %1, %29, off\n\t"
        "global_load_dwordx4 %2, %30, off\n\t"
        "global_load_dwordx4 %3, %31, off\n\t"
        "global_load_dwordx4 %4, %32, off\n\t"
        "global_load_dwordx4 %5, %33, off\n\t"
        "global_load_dwordx4 %6, %34, off\n\t"
        "global_load_dwordx4 %7, %35, off\n\t"
        "global_load_dwordx4 %8, %36, off\n\t"
        "global_load_dwordx4 %9, %37, off\n\t"
        "global_load_dwordx4 %10, %38, off\n\t"
        "global_load_dwordx4 %11, %39, off\n\t"
        "global_load_dwordx4 %12, %40, off\n\t"
        "global_load_dwordx4 %13, %41, off\n\t"
        "global_load_dwordx4 %14, %42, off\n\t"
        "global_load_dwordx4 %15, %43, off\n\t"
        "global_load_dwordx4 %16, %44, off\n\t"
        "global_load_dwordx4 %17, %45, off\n\t"
        "global_load_dwordx4 %18, %46, off\n\t"
        "global_load_dwordx4 %19, %47, off\n\t"
        "global_load_dwordx4 %20, %48, off\n\t"
        "global_load_dwordx4 %21, %49, off\n\t"
        "global_load_dwordx4 %22, %50, off\n\t"
        "global_load_dwordx4 %23, %51, off\n\t"
        "global_load_dword %24, %52, off\n\t"
        "global_load_dword %25, %53, off\n\t"
        "global_load_dword %26, %54, off\n\t"
        "global_load_dword %27, %55, off\n\t"
        "s_waitcnt vmcnt(0)"
        : "=&v"(B[0][0][0]), "=&v"(B[0][0][1]), "=&v"(B[0][1][0]), "=&v"(B[0][1][1]),
          "=&v"(B[0][2][0]), "=&v"(B[0][2][1]), "=&v"(B[1][0][0]), "=&v"(B[1][0][1]),
          "=&v"(B[1][1][0]), "=&v"(B[1][1][1]), "=&v"(B[1][2][0]), "=&v"(B[1][2][1]),
          "=&v"(B[2][0][0]), "=&v"(B[2][0][1]), "=&v"(B[2][1][0]), "=&v"(B[2][1][1]),
          "=&v"(B[2][2][0]), "=&v"(B[2][2][1]), "=&v"(B[3][0][0]), "=&v"(B[3][0][1]),
          "=&v"(B[3][1][0]), "=&v"(B[3][1][1]), "=&v"(B[3][2][0]), "=&v"(B[3][2][1]),
          "=&v"(IVw[0]), "=&v"(IVw[1]), "=&v"(IVw[2]), "=&v"(IVw[3])
        : "v"(ap[0][0][0]), "v"(ap[0][0][1]), "v"(ap[0][1][0]), "v"(ap[0][1][1]),
          "v"(ap[0][2][0]), "v"(ap[0][2][1]), "v"(ap[1][0][0]), "v"(ap[1][0][1]),
          "v"(ap[1][1][0]), "v"(ap[1][1][1]), "v"(ap[1][2][0]), "v"(ap[1][2][1]),
          "v"(ap[2][0][0]), "v"(ap[2][0][1]), "v"(ap[2][1][0]), "v"(ap[2][1][1]),
          "v"(ap[2][2][0]), "v"(ap[2][2][1]), "v"(ap[3][0][0]), "v"(ap[3][0][1]),
          "v"(ap[3][1][0]), "v"(ap[3][1][1]), "v"(ap[3][2][0]), "v"(ap[3][2][1]),
          "v"(ip[0]), "v"(ip[1]), "v"(ip[2]), "v"(ip[3])
        : "memory");

    // ---- expand IV scalars from row values via shuffles ----
    float IV[4][3][2];
    #pragma unroll
    for (int w = 0; w < 4; ++w)
        #pragma unroll
        for (int dw = 0; dw < 3; ++dw)
            #pragma unroll
            for (int nt = 0; nt < 2; ++nt) {
                const float s = __shfl(IVw[w], nt * 16 + l15 + dw, 64);
                IV[w][dw][nt] = (rokv[w] & cok[nt][dw]) ? s : 0.f;
            }

    f32x4 acc[2][4][2];
    #pragma unroll
    for (int ri = 0; ri < 2; ++ri)
        #pragma unroll
        for (int m = 0; m < 4; ++m)
            #pragma unroll
            for (int nt = 0; nt < 2; ++nt)
                acc[ri][m][nt] = (f32x4){0.f, 0.f, 0.f, 0.f};

    #pragma unroll
    for (int dh = 0; dh < 3; ++dh) {
        #pragma unroll
        for (int dw = 0; dw < 3; ++dw) {
            const int t = dh * 3 + dw;
            #pragma unroll
            for (int m = 0; m < 4; ++m) {
                const i32x4 af = *reinterpret_cast<const i32x4*>(
                    wbuf + (((t << 2) + m) << 10) + (lane << 4));
                #pragma unroll
                for (int ri = 0; ri < 2; ++ri) {
                    const int w = ri + dh;
                    #pragma unroll
                    for (int nt = 0; nt < 2; ++nt) {
                        i32x4 tap = __builtin_amdgcn_mfma_i32_16x16x64_i8(
                            af, B[w][dw][nt], (i32x4){0, 0, 0, 0}, 0, 0, 0);
                        f32x4 tf;
                        tf[0] = (float)tap[0]; tf[1] = (float)tap[1];
                        tf[2] = (float)tap[2]; tf[3] = (float)tap[3];
                        acc[ri][m][nt] += tf * IV[w][dw][nt];
                    }
                }
            }
        }
    }

    // ---- epilogue: 2 row passes through a single-row per-wave LDS buffer ----
    const float wm = wm_ptr[0];
    float bias_v[4][4];
    #pragma unroll
    for (int m = 0; m < 4; ++m)
        #pragma unroll
        for (int r = 0; r < 4; ++r)
            bias_v[m][r] = bias[(m << 4) + (lg << 2) + r];

    #pragma unroll
    for (int ri = 0; ri < 2; ++ri) {
        #pragma unroll
        for (int m = 0; m < 4; ++m)
            #pragma unroll
            for (int nt = 0; nt < 2; ++nt)
                #pragma unroll
                for (int r = 0; r < 4; ++r)
                    eplds[wv][(m << 4) + (lg << 2) + r][(nt << 4) + l15] =
                        fmaf(acc[ri][m][nt][r], wm, bias_v[m][r]);

        // same-wave LDS readback; each 8-lane group covers one full 128-B line
        // REGULAR stores (the A/B variable): complete at L2, flush lazily.
        const int gh = gh0 + ri;
        #pragma unroll
        for (int j = 0; j < 8; ++j) {
            const int o   = (j << 3) + (lane >> 3);
            const int px0 = (lane & 7) << 2;
            const f32x4 v = *reinterpret_cast<const f32x4*>(&eplds[wv][o][px0]);
            float* dst = out + ((((size_t)n << 6) + o) << 16) + (gh << 8) + w0 + px0;
            *reinterpret_cast<f32x4*>(dst) = v;
        }
    }
}

// ===========================================================================
// Fallback (round-1, verified): fused bf16 kernel pair, needs ~74 KB of ws.
// ===========================================================================
#define HALO_W 34
#define NPIX 340

__global__ __launch_bounds__(256) void wq_kernel(const float* __restrict__ w,
                                                 float* __restrict__ wm_out,
                                                 u16* __restrict__ wbuf) {
    __shared__ float red[4];
    __shared__ float wm_sh;
    const int tid = threadIdx.x;

    float s = 0.f;
    for (int i = tid; i < XO * XC * 9; i += 256) s += fabsf(w[i]);
    #pragma unroll
    for (int off = 32; off > 0; off >>= 1) s += __shfl_down(s, off, 64);
    if ((tid & 63) == 0) red[tid >> 6] = s;
    __syncthreads();
    if (tid == 0) {
        float tot = red[0] + red[1] + red[2] + red[3];
        float wm = fmaxf(tot / (float)(XO * XC * 9), 1e-5f);
        wm_out[0] = wm;
        wm_sh = wm;
    }
    __syncthreads();
    const float wscale = 1.0f / wm_sh;

    for (int idx = tid; idx < XO * XC * 9; idx += 256) {
        const int j = idx & 7;
        const int l = (idx >> 3) & 63;
        const int c = (idx >> 9) & 1;
        const int m = (idx >> 10) & 3;
        const int t = idx >> 12;
        const int o = m * 16 + (l & 15);
        const int i = c * 32 + (l >> 4) * 8 + j;
        const int kh = t / 3, kw = t % 3;
        const float wv = w[((o * XC + i) * 3 + kh) * 3 + kw];
        const float tern = fminf(fmaxf(rintf(wv * wscale), -1.f), 1.f);
        wbuf[idx] = (u16)(__float_as_uint(tern) >> 16);
    }
}

__global__ __launch_bounds__(256) void conv_kernel(const float* __restrict__ x,
                                                   const u16* __restrict__ wbuf,
                                                   const float* __restrict__ wm_ptr,
                                                   const float* __restrict__ bias,
                                                   float* __restrict__ out) {
    __shared__ __align__(16) u16 q_lds[NPIX * 64];
    __shared__ float invs_lds[NPIX];
    __shared__ float bias_lds[XO];

    const int tid = threadIdx.x;
    const int bid = blockIdx.x;
    const int n   = bid >> 8;
    const int rem = bid & 255;
    const int h0  = (rem >> 3) << 3;
    const int w0  = (rem & 7) << 5;

    if (tid < XO) bias_lds[tid] = bias[tid];

    #pragma unroll 1
    for (int p = tid; p < NPIX; p += 256) {
        const int hr = p / HALO_W;
        const int cl = p - hr * HALO_W;
        const int gh = h0 + hr - 1;
        const int gw = w0 + cl - 1;
        const bool ok = (gh >= 0) & (gh < XH) & (gw >= 0) & (gw < XW);

        float vals[64];
        float amax = 0.f;
        if (ok) {
            const float* px = x + (size_t)n * (XC * CH_STRIDE) + (size_t)gh * XW + gw;
            #pragma unroll
            for (int c = 0; c < 64; ++c) {
                const float v = px[(size_t)c * CH_STRIDE];
                vals[c] = v;
                amax = fmaxf(amax, fabsf(v));
            }
        } else {
            #pragma unroll
            for (int c = 0; c < 64; ++c) vals[c] = 0.f;
        }
        const float am    = fmaxf(amax, 1e-5f);
        const float scale = 127.0f / am;
        invs_lds[p] = ok ? (1.0f / scale) : 0.0f;

        const int sw = (p & 7) << 3;
        #pragma unroll
        for (int cb = 0; cb < 8; ++cb) {
            u16x8 pk;
            #pragma unroll
            for (int j = 0; j < 8; ++j) {
                const float q = fminf(fmaxf(rintf(vals[cb * 8 + j] * scale), -128.f), 127.f);
                pk[j] = (u16)(__float_as_uint(q) >> 16);
            }
            *reinterpret_cast<u16x8*>(&q_lds[p * 64 + ((cb * 8) ^ sw)]) = pk;
        }
    }
    __syncthreads();

    const int lane = tid & 63;
    const int wv   = tid >> 6;
    const int l15  = lane & 15;
    const int lg   = lane >> 4;

    f32x4 acc[4][4];
    #pragma unroll
    for (int m = 0; m < 4; ++m)
        #pragma unroll
        for (int nt = 0; nt < 4; ++nt) acc[m][nt] = (f32x4){0.f, 0.f, 0.f, 0.f};

    const float wm = wm_ptr[0];

    #pragma unroll
    for (int t = 0; t < 9; ++t) {
        const int dh = t / 3, dw = t % 3;

        short8 afr[4][2];
        #pragma unroll
        for (int m = 0; m < 4; ++m)
            #pragma unroll
            for (int c = 0; c < 2; ++c)
                afr[m][c] = *reinterpret_cast<const short8*>(
                    wbuf + ((((t * 4 + m) * 2 + c) * 64 + lane) * 8));

        #pragma unroll
        for (int nt = 0; nt < 4; ++nt) {
            const int rl  = 2 * wv + (nt >> 1);
            const int pix = (rl + dh) * HALO_W + (nt & 1) * 16 + l15 + dw;
            const int sw  = (pix & 7) << 3;
            const u16* qp = &q_lds[pix * 64];
            const short8 b0 = *reinterpret_cast<const short8*>(qp + ((lg * 8) ^ sw));
            const short8 b1 = *reinterpret_cast<const short8*>(qp + ((32 + lg * 8) ^ sw));
            const float  iv = invs_lds[pix];
            #pragma unroll
            for (int m = 0; m < 4; ++m) {
                f32x4 tap = (f32x4){0.f, 0.f, 0.f, 0.f};
                tap = __builtin_amdgcn_mfma_f32_16x16x32_bf16(afr[m][0], b0, tap, 0, 0, 0);
                tap = __builtin_amdgcn_mfma_f32_16x16x32_bf16(afr[m][1], b1, tap, 0, 0, 0);
                acc[m][nt] += tap * iv;
            }
        }
    }

    #pragma unroll
    for (int m = 0; m < 4; ++m) {
        #pragma unroll
        for (int nt = 0; nt < 4; ++nt) {
            const int rl = 2 * wv + (nt >> 1);
            const int gh = h0 + rl;
            const int gw = w0 + (nt & 1) * 16 + l15;
            #pragma unroll
            for (int r = 0; r < 4; ++r) {
                const int o = m * 16 + lg * 4 + r;
                const float v = wm * acc[m][nt][r] + bias_lds[o];
                out[(((size_t)n * XO + o) * XH + gh) * XW + gw] = v;
            }
        }
    }
}

extern "C" void kernel_launch(void* const* d_in, const int* in_sizes, int n_in,
                              void* d_out, int out_size, void* d_ws, size_t ws_size,
                              hipStream_t stream) {
    const float* x    = (const float*)d_in[0];
    const float* w    = (const float*)d_in[1];
    const float* bias = (const float*)d_in[2];
    float* out = (float*)d_out;

    if (ws_size >= (size_t)WS_NEED) {
        signed char* qx       = (signed char*)d_ws;
        float*       invsb    = (float*)((char*)d_ws + INVS_OFF);
        signed char* wbuf     = (signed char*)((char*)d_ws + WBUF_OFF);
        float*       partials = (float*)((char*)d_ws + PART_OFF);
        float*       wm       = (float*)((char*)d_ws + WM_OFF);

        wq_reduce<<<64, 256, 0, stream>>>(w, partials);
        wq_tern_i8<<<144, 256, 0, stream>>>(w, partials, wm, wbuf);
        aq_i8<<<XN * 256, 256, 0, stream>>>(x, qx, invsb);
        conv_i8<<<XN * 256, 256, 0, stream>>>(qx, invsb, wbuf, wm, bias, out);
    } else {
        float* wsf  = (float*)d_ws;
        u16*   wbuf = (u16*)((char*)d_ws + 64);
        wq_kernel<<<1, 256, 0, stream>>>(w, wsf, wbuf);
        conv_kernel<<<XN * 256, 256, 0, stream>>>(x, wbuf, wsf, bias, out);
    }
}

// Round 18
// 164.004 us; speedup vs baseline: 1.2906x; 1.2906x over previous
//
#include <hip/hip_runtime.h>
#include <hip/hip_bf16.h>

typedef __attribute__((ext_vector_type(8))) short short8;
typedef __attribute__((ext_vector_type(4))) float f32x4;
typedef __attribute__((ext_vector_type(4))) int i32x4;
typedef unsigned short u16;
typedef unsigned int u32;
typedef __attribute__((ext_vector_type(8))) unsigned short u16x8;
typedef __attribute__((ext_vector_type(4))) u32 u32x4;

#define XN 16
#define XC 64
#define XH 256
#define XW 256
#define XO 64
#define CH_STRIDE (XH * XW)   // 65536

// ---- i8 path ws layout (bytes) ----
#define QX_OFF    0                         // i8[16*256*256*64] = 67,108,864 (pixel-major NHWC)
#define INVS_OFF  67108864                  // f32[1048576] = 4,194,304
#define WBUF_OFF  71303168                  // i8[36864]
#define PART_OFF  71340032                  // f32[64]
#define WM_OFF    71340288                  // f32[1]
#define WS_NEED   71340544

// ---------------------------------------------------------------------------
// Weight quant stage 1: deterministic partial |w| sums (64 blocks x 576 elems).
// ---------------------------------------------------------------------------
__global__ __launch_bounds__(256) void wq_reduce(const float* __restrict__ w,
                                                 float* __restrict__ partials) {
    __shared__ float red[4];
    const int tid = threadIdx.x;
    const int base = blockIdx.x * 576;       // 36864 / 64
    float s = 0.f;
    for (int i = tid; i < 576; i += 256) s += fabsf(w[base + i]);
    #pragma unroll
    for (int off = 32; off > 0; off >>= 1) s += __shfl_down(s, off, 64);
    if ((tid & 63) == 0) red[tid >> 6] = s;
    __syncthreads();
    if (tid == 0) partials[blockIdx.x] = red[0] + red[1] + red[2] + red[3];
}

// ---------------------------------------------------------------------------
// Weight quant stage 2: ternarize to i8 in MFMA A-fragment layout (144 blocks).
//   idx = ((t*4 + m)*64 + l)*16 + j
//   holds tern[o = m*16 + (l&15)][i = (l>>4)*16 + j]  for tap t
// ---------------------------------------------------------------------------
__global__ __launch_bounds__(256) void wq_tern_i8(const float* __restrict__ w,
                                                  const float* __restrict__ partials,
                                                  float* __restrict__ wm_out,
                                                  signed char* __restrict__ wbuf) {
    __shared__ float wm_sh;
    const int tid = threadIdx.x;
    if (tid == 0) {
        float tot = 0.f;
        #pragma unroll
        for (int i = 0; i < 64; ++i) tot += partials[i];   // fixed order: deterministic
        float wm = fmaxf(tot / (float)(XO * XC * 9), 1e-5f);
        wm_sh = wm;
        if (blockIdx.x == 0) wm_out[0] = wm;
    }
    __syncthreads();
    const float wscale = 1.0f / wm_sh;

    const int idx = blockIdx.x * 256 + tid;  // < 36864
    const int j = idx & 15;
    const int l = (idx >> 4) & 63;
    const int m = (idx >> 10) & 3;
    const int t = idx >> 12;                 // 0..8
    const int o = m * 16 + (l & 15);
    const int i = (l >> 4) * 16 + j;
    const int kh = t / 3, kw = t % 3;
    const float wv = w[((o * XC + i) * 3 + kh) * 3 + kw];
    const float tern = fminf(fmaxf(rintf(wv * wscale), -1.f), 1.f);
    wbuf[idx] = (signed char)(int)tern;
}

// ---------------------------------------------------------------------------
// Activation quant: one block per (n,h) row. qx = i8, pixel-major (64 B/px,
// channels contiguous). invs = amax/127 per pixel.
// ---------------------------------------------------------------------------
__global__ __launch_bounds__(256) void aq_i8(const float* __restrict__ x,
                                             signed char* __restrict__ qx,
                                             float* __restrict__ invs) {
    const int tid = threadIdx.x;
    const int b = blockIdx.x;            // 4096 = 16*256
    const int n = b >> 8;

    const float* px = x + ((size_t)n << 22) + ((size_t)(b & 255) << 8) + tid;
    float vals[64];
    float amax = 0.f;
    #pragma unroll
    for (int c = 0; c < 64; ++c) {
        const float v = px[(size_t)c << 16];
        vals[c] = v;
        amax = fmaxf(amax, fabsf(v));
    }
    const float am = fmaxf(amax, 1e-5f);
    const float scale = 127.0f / am;
    invs[((size_t)b << 8) + tid] = am * (1.0f / 127.0f);

    u32 words[16];
    #pragma unroll
    for (int wk = 0; wk < 16; ++wk) {
        u32 acc = 0;
        #pragma unroll
        for (int bb = 0; bb < 4; ++bb) {
            const float q = fminf(fmaxf(rintf(vals[wk * 4 + bb] * scale), -128.f), 127.f);
            acc |= ((u32)((int)q) & 255u) << (bb * 8);
        }
        words[wk] = acc;
    }
    u32* dst = (u32*)(qx + ((((size_t)b << 8) + tid) << 6));
    #pragma unroll
    for (int i = 0; i < 4; ++i) {
        *reinterpret_cast<u32x4*>(dst + i * 4) =
            (u32x4){words[i * 4], words[i * 4 + 1], words[i * 4 + 2], words[i * 4 + 3]};
    }
}

// ---------------------------------------------------------------------------
// Conv (round-16 verified best, 164.4 µs): wave = 2 output rows x 32 px x
// 64 out-ch. All 24 B-fragment dwordx4 loads + 4 IV row dword loads in ONE
// asm volatile (early-clobber outputs, s_waitcnt vmcnt(0) inside) -> single
// latency exposure. IV scalars expanded via __shfl. 144 i8 MFMAs + dequant.
// Epilogue: two-pass same-wave LDS transpose -> full-128B-line NONTEMPORAL
// stores (r17 A/B: regular cached stores +47 µs — NT avoids L2 contention
// between the qx read stream and the 268 MB output write stream).
// __launch_bounds__(256,2): VGPR cap 256 — no spill (round-14 safety rule).
// ---------------------------------------------------------------------------
__global__ __launch_bounds__(256, 2) void conv_i8(const signed char* __restrict__ qx,
                                                  const float* __restrict__ invs,
                                                  const signed char* __restrict__ wbuf,
                                                  const float* __restrict__ wm_ptr,
                                                  const float* __restrict__ bias,
                                                  float* __restrict__ out) {
    __shared__ float eplds[4][64][36];   // 36,864 B; per-wave private, reused per row

    const int tid = threadIdx.x;
    // bijective XCD swizzle: 4096 blocks, 512 per XCD
    const int bid = (blockIdx.x & 7) * 512 + (blockIdx.x >> 3);
    const int n      = bid >> 8;           // 256 blocks/image
    const int rem    = bid & 255;
    const int rowgrp = rem >> 3;           // 0..31 (8 rows each)
    const int w0     = (rem & 7) << 5;     // 0..224
    const int wv     = tid >> 6;
    const int gh0    = (rowgrp << 3) + (wv << 1);  // wave's first output row
    const int lane = tid & 63;
    const int l15 = lane & 15;
    const int lg  = lane >> 4;

    const signed char* qn = qx + ((size_t)n << 22);          // n * 256*256*64
    const float*       in = invs + ((size_t)n << 16);

    // per-lane clamped cols for nt in {0,1}, dw in {0,1,2}
    int gwc[2][3]; bool cok[2][3];
    #pragma unroll
    for (int nt = 0; nt < 2; ++nt)
        #pragma unroll
        for (int dw = 0; dw < 3; ++dw) {
            const int gw = w0 + nt * 16 + l15 + dw - 1;
            cok[nt][dw] = (gw >= 0) & (gw < XW);
            gwc[nt][dw] = min(max(gw, 0), XW - 1);
        }
    // IV row-load column: lane covers halo cols w0-1 .. w0+62 (need w0-1..w0+33)
    const int ivcol = min(max(w0 + lane - 1, 0), XW - 1);

    // ---- addresses for the mega-batch ----
    const signed char* ap[4][3][2];
    const float*       ip[4];
    bool rokv[4];
    #pragma unroll
    for (int w = 0; w < 4; ++w) {
        const int gh = gh0 + w - 1;
        rokv[w] = (gh >= 0) & (gh < XH);
        const int ghc = min(max(gh, 0), XH - 1);
        const signed char* qrow = qn + ((size_t)ghc << 14);   // 256 px * 64 B
        ip[w] = in + (ghc << 8) + ivcol;
        #pragma unroll
        for (int dw = 0; dw < 3; ++dw)
            #pragma unroll
            for (int nt = 0; nt < 2; ++nt)
                ap[w][dw][nt] = qrow + (gwc[nt][dw] << 6) + (lg << 4);
    }

    // ---- THE batch: 24 dwordx4 + 4 dword in ONE asm statement, drained inside
    i32x4 B[4][3][2];
    float IVw[4];
    asm volatile(
        "global_load_dwordx4 %0, %28, off\n\t"
        "global_load_dwordx4 %1, %29, off\n\t"
        "global_load_dwordx4 %2, %30, off\n\t"
        "global_load_dwordx4 %3, %31, off\n\t"
        "global_load_dwordx4 %4, %32, off\n\t"
        "global_load_dwordx4 %5, %33, off\n\t"
        "global_load_dwordx4 %6, %34, off\n\t"
        "global_load_dwordx4 %7, %35, off\n\t"
        "global_load_dwordx4 %8, %36, off\n\t"
        "global_load_dwordx4 %9, %37, off\n\t"
        "global_load_dwordx4 %10, %38, off\n\t"
        "global_load_dwordx4 %11, %39, off\n\t"
        "global_load_dwordx4 %12, %40, off\n\t"
        "global_load_dwordx4 %13, %41, off\n\t"
        "global_load_dwordx4 %14, %42, off\n\t"
        "global_load_dwordx4 %15, %43, off\n\t"
        "global_load_dwordx4 %16, %44, off\n\t"
        "global_load_dwordx4 %17, %45, off\n\t"
        "global_load_dwordx4 %18, %46, off\n\t"
        "global_load_dwordx4 %19, %47, off\n\t"
        "global_load_dwordx4 %20, %48, off\n\t"
        "global_load_dwordx4 %21, %49, off\n\t"
        "global_load_dwordx4 %22, %50, off\n\t"
        "global_load_dwordx4 %23, %51, off\n\t"
        "global_load_dword %24, %52, off\n\t"
        "global_load_dword %25, %53, off\n\t"
        "global_load_dword %26, %54, off\n\t"
        "global_load_dword %27, %55, off\n\t"
        "s_waitcnt vmcnt(0)"
        : "=&v"(B[0][0][0]), "=&v"(B[0][0][1]), "=&v"(B[0][1][0]), "=&v"(B[0][1][1]),
          "=&v"(B[0][2][0]), "=&v"(B[0][2][1]), "=&v"(B[1][0][0]), "=&v"(B[1][0][1]),
          "=&v"(B[1][1][0]), "=&v"(B[1][1][1]), "=&v"(B[1][2][0]), "=&v"(B[1][2][1]),
          "=&v"(B[2][0][0]), "=&v"(B[2][0][1]), "=&v"(B[2][1][0]), "=&v"(B[2][1][1]),
          "=&v"(B[2][2][0]), "=&v"(B[2][2][1]), "=&v"(B[3][0][0]), "=&v"(B[3][0][1]),
          "=&v"(B[3][1][0]), "=&v"(B[3][1][1]), "=&v"(B[3][2][0]), "=&v"(B[3][2][1]),
          "=&v"(IVw[0]), "=&v"(IVw[1]), "=&v"(IVw[2]), "=&v"(IVw[3])
        : "v"(ap[0][0][0]), "v"(ap[0][0][1]), "v"(ap[0][1][0]), "v"(ap[0][1][1]),
          "v"(ap[0][2][0]), "v"(ap[0][2][1]), "v"(ap[1][0][0]), "v"(ap[1][0][1]),
          "v"(ap[1][1][0]), "v"(ap[1][1][1]), "v"(ap[1][2][0]), "v"(ap[1][2][1]),
          "v"(ap[2][0][0]), "v"(ap[2][0][1]), "v"(ap[2][1][0]), "v"(ap[2][1][1]),
          "v"(ap[2][2][0]), "v"(ap[2][2][1]), "v"(ap[3][0][0]), "v"(ap[3][0][1]),
          "v"(ap[3][1][0]), "v"(ap[3][1][1]), "v"(ap[3][2][0]), "v"(ap[3][2][1]),
          "v"(ip[0]), "v"(ip[1]), "v"(ip[2]), "v"(ip[3])
        : "memory");

    // ---- expand IV scalars from row values via shuffles ----
    float IV[4][3][2];
    #pragma unroll
    for (int w = 0; w < 4; ++w)
        #pragma unroll
        for (int dw = 0; dw < 3; ++dw)
            #pragma unroll
            for (int nt = 0; nt < 2; ++nt) {
                const float s = __shfl(IVw[w], nt * 16 + l15 + dw, 64);
                IV[w][dw][nt] = (rokv[w] & cok[nt][dw]) ? s : 0.f;
            }

    f32x4 acc[2][4][2];
    #pragma unroll
    for (int ri = 0; ri < 2; ++ri)
        #pragma unroll
        for (int m = 0; m < 4; ++m)
            #pragma unroll
            for (int nt = 0; nt < 2; ++nt)
                acc[ri][m][nt] = (f32x4){0.f, 0.f, 0.f, 0.f};

    #pragma unroll
    for (int dh = 0; dh < 3; ++dh) {
        #pragma unroll
        for (int dw = 0; dw < 3; ++dw) {
            const int t = dh * 3 + dw;
            #pragma unroll
            for (int m = 0; m < 4; ++m) {
                const i32x4 af = *reinterpret_cast<const i32x4*>(
                    wbuf + (((t << 2) + m) << 10) + (lane << 4));
                #pragma unroll
                for (int ri = 0; ri < 2; ++ri) {
                    const int w = ri + dh;
                    #pragma unroll
                    for (int nt = 0; nt < 2; ++nt) {
                        i32x4 tap = __builtin_amdgcn_mfma_i32_16x16x64_i8(
                            af, B[w][dw][nt], (i32x4){0, 0, 0, 0}, 0, 0, 0);
                        f32x4 tf;
                        tf[0] = (float)tap[0]; tf[1] = (float)tap[1];
                        tf[2] = (float)tap[2]; tf[3] = (float)tap[3];
                        acc[ri][m][nt] += tf * IV[w][dw][nt];
                    }
                }
            }
        }
    }

    // ---- epilogue: 2 row passes through a single-row per-wave LDS buffer ----
    const float wm = wm_ptr[0];
    float bias_v[4][4];
    #pragma unroll
    for (int m = 0; m < 4; ++m)
        #pragma unroll
        for (int r = 0; r < 4; ++r)
            bias_v[m][r] = bias[(m << 4) + (lg << 2) + r];

    #pragma unroll
    for (int ri = 0; ri < 2; ++ri) {
        #pragma unroll
        for (int m = 0; m < 4; ++m)
            #pragma unroll
            for (int nt = 0; nt < 2; ++nt)
                #pragma unroll
                for (int r = 0; r < 4; ++r)
                    eplds[wv][(m << 4) + (lg << 2) + r][(nt << 4) + l15] =
                        fmaf(acc[ri][m][nt][r], wm, bias_v[m][r]);

        // same-wave LDS readback; each 8-lane group covers one full 128-B line
        const int gh = gh0 + ri;
        #pragma unroll
        for (int j = 0; j < 8; ++j) {
            const int o   = (j << 3) + (lane >> 3);
            const int px0 = (lane & 7) << 2;
            const f32x4 v = *reinterpret_cast<const f32x4*>(&eplds[wv][o][px0]);
            float* dst = out + ((((size_t)n << 6) + o) << 16) + (gh << 8) + w0 + px0;
            __builtin_nontemporal_store(v, reinterpret_cast<f32x4*>(dst));
        }
    }
}

// ===========================================================================
// Fallback (round-1, verified): fused bf16 kernel pair, needs ~74 KB of ws.
// ===========================================================================
#define HALO_W 34
#define NPIX 340

__global__ __launch_bounds__(256) void wq_kernel(const float* __restrict__ w,
                                                 float* __restrict__ wm_out,
                                                 u16* __restrict__ wbuf) {
    __shared__ float red[4];
    __shared__ float wm_sh;
    const int tid = threadIdx.x;

    float s = 0.f;
    for (int i = tid; i < XO * XC * 9; i += 256) s += fabsf(w[i]);
    #pragma unroll
    for (int off = 32; off > 0; off >>= 1) s += __shfl_down(s, off, 64);
    if ((tid & 63) == 0) red[tid >> 6] = s;
    __syncthreads();
    if (tid == 0) {
        float tot = red[0] + red[1] + red[2] + red[3];
        float wm = fmaxf(tot / (float)(XO * XC * 9), 1e-5f);
        wm_out[0] = wm;
        wm_sh = wm;
    }
    __syncthreads();
    const float wscale = 1.0f / wm_sh;

    for (int idx = tid; idx < XO * XC * 9; idx += 256) {
        const int j = idx & 7;
        const int l = (idx >> 3) & 63;
        const int c = (idx >> 9) & 1;
        const int m = (idx >> 10) & 3;
        const int t = idx >> 12;
        const int o = m * 16 + (l & 15);
        const int i = c * 32 + (l >> 4) * 8 + j;
        const int kh = t / 3, kw = t % 3;
        const float wv = w[((o * XC + i) * 3 + kh) * 3 + kw];
        const float tern = fminf(fmaxf(rintf(wv * wscale), -1.f), 1.f);
        wbuf[idx] = (u16)(__float_as_uint(tern) >> 16);
    }
}

__global__ __launch_bounds__(256) void conv_kernel(const float* __restrict__ x,
                                                   const u16* __restrict__ wbuf,
                                                   const float* __restrict__ wm_ptr,
                                                   const float* __restrict__ bias,
                                                   float* __restrict__ out) {
    __shared__ __align__(16) u16 q_lds[NPIX * 64];
    __shared__ float invs_lds[NPIX];
    __shared__ float bias_lds[XO];

    const int tid = threadIdx.x;
    const int bid = blockIdx.x;
    const int n   = bid >> 8;
    const int rem = bid & 255;
    const int h0  = (rem >> 3) << 3;
    const int w0  = (rem & 7) << 5;

    if (tid < XO) bias_lds[tid] = bias[tid];

    #pragma unroll 1
    for (int p = tid; p < NPIX; p += 256) {
        const int hr = p / HALO_W;
        const int cl = p - hr * HALO_W;
        const int gh = h0 + hr - 1;
        const int gw = w0 + cl - 1;
        const bool ok = (gh >= 0) & (gh < XH) & (gw >= 0) & (gw < XW);

        float vals[64];
        float amax = 0.f;
        if (ok) {
            const float* px = x + (size_t)n * (XC * CH_STRIDE) + (size_t)gh * XW + gw;
            #pragma unroll
            for (int c = 0; c < 64; ++c) {
                const float v = px[(size_t)c * CH_STRIDE];
                vals[c] = v;
                amax = fmaxf(amax, fabsf(v));
            }
        } else {
            #pragma unroll
            for (int c = 0; c < 64; ++c) vals[c] = 0.f;
        }
        const float am    = fmaxf(amax, 1e-5f);
        const float scale = 127.0f / am;
        invs_lds[p] = ok ? (1.0f / scale) : 0.0f;

        const int sw = (p & 7) << 3;
        #pragma unroll
        for (int cb = 0; cb < 8; ++cb) {
            u16x8 pk;
            #pragma unroll
            for (int j = 0; j < 8; ++j) {
                const float q = fminf(fmaxf(rintf(vals[cb * 8 + j] * scale), -128.f), 127.f);
                pk[j] = (u16)(__float_as_uint(q) >> 16);
            }
            *reinterpret_cast<u16x8*>(&q_lds[p * 64 + ((cb * 8) ^ sw)]) = pk;
        }
    }
    __syncthreads();

    const int lane = tid & 63;
    const int wv   = tid >> 6;
    const int l15  = lane & 15;
    const int lg   = lane >> 4;

    f32x4 acc[4][4];
    #pragma unroll
    for (int m = 0; m < 4; ++m)
        #pragma unroll
        for (int nt = 0; nt < 4; ++nt) acc[m][nt] = (f32x4){0.f, 0.f, 0.f, 0.f};

    const float wm = wm_ptr[0];

    #pragma unroll
    for (int t = 0; t < 9; ++t) {
        const int dh = t / 3, dw = t % 3;

        short8 afr[4][2];
        #pragma unroll
        for (int m = 0; m < 4; ++m)
            #pragma unroll
            for (int c = 0; c < 2; ++c)
                afr[m][c] = *reinterpret_cast<const short8*>(
                    wbuf + ((((t * 4 + m) * 2 + c) * 64 + lane) * 8));

        #pragma unroll
        for (int nt = 0; nt < 4; ++nt) {
            const int rl  = 2 * wv + (nt >> 1);
            const int pix = (rl + dh) * HALO_W + (nt & 1) * 16 + l15 + dw;
            const int sw  = (pix & 7) << 3;
            const u16* qp = &q_lds[pix * 64];
            const short8 b0 = *reinterpret_cast<const short8*>(qp + ((lg * 8) ^ sw));
            const short8 b1 = *reinterpret_cast<const short8*>(qp + ((32 + lg * 8) ^ sw));
            const float  iv = invs_lds[pix];
            #pragma unroll
            for (int m = 0; m < 4; ++m) {
                f32x4 tap = (f32x4){0.f, 0.f, 0.f, 0.f};
                tap = __builtin_amdgcn_mfma_f32_16x16x32_bf16(afr[m][0], b0, tap, 0, 0, 0);
                tap = __builtin_amdgcn_mfma_f32_16x16x32_bf16(afr[m][1], b1, tap, 0, 0, 0);
                acc[m][nt] += tap * iv;
            }
        }
    }

    #pragma unroll
    for (int m = 0; m < 4; ++m) {
        #pragma unroll
        for (int nt = 0; nt < 4; ++nt) {
            const int rl = 2 * wv + (nt >> 1);
            const int gh = h0 + rl;
            const int gw = w0 + (nt & 1) * 16 + l15;
            #pragma unroll
            for (int r = 0; r < 4; ++r) {
                const int o = m * 16 + lg * 4 + r;
                const float v = wm * acc[m][nt][r] + bias_lds[o];
                out[(((size_t)n * XO + o) * XH + gh) * XW + gw] = v;
            }
        }
    }
}

extern "C" void kernel_launch(void* const* d_in, const int* in_sizes, int n_in,
                              void* d_out, int out_size, void* d_ws, size_t ws_size,
                              hipStream_t stream) {
    const float* x    = (const float*)d_in[0];
    const float* w    = (const float*)d_in[1];
    const float* bias = (const float*)d_in[2];
    float* out = (float*)d_out;

    if (ws_size >= (size_t)WS_NEED) {
        signed char* qx       = (signed char*)d_ws;
        float*       invsb    = (float*)((char*)d_ws + INVS_OFF);
        signed char* wbuf     = (signed char*)((char*)d_ws + WBUF_OFF);
        float*       partials = (float*)((char*)d_ws + PART_OFF);
        float*       wm       = (float*)((char*)d_ws + WM_OFF);

        wq_reduce<<<64, 256, 0, stream>>>(w, partials);
        wq_tern_i8<<<144, 256, 0, stream>>>(w, partials, wm, wbuf);
        aq_i8<<<XN * 256, 256, 0, stream>>>(x, qx, invsb);
        conv_i8<<<XN * 256, 256, 0, stream>>>(qx, invsb, wbuf, wm, bias, out);
    } else {
        float* wsf  = (float*)d_ws;
        u16*   wbuf = (u16*)((char*)d_ws + 64);
        wq_kernel<<<1, 256, 0, stream>>>(w, wsf, wbuf);
        conv_kernel<<<XN * 256, 256, 0, stream>>>(x, wbuf, wsf, bias, out);
    }
}